// Round 2
// baseline (184.843 us; speedup 1.0000x reference)
//
#include <hip/hip_runtime.h>

// CSR SpMV, 32 nnz/row exactly (uniform row_ptrs), ROWS=COLS=1e6.
//
// R2: 4 lanes per row (8 gathers/thread for deeper memory-level parallelism),
// non-temporal loads on the read-once values/col_indices streams so they do
// not evict the 4 MB x vector from each XCD's 4 MiB L2.

typedef float f32x4 __attribute__((ext_vector_type(4)));
typedef int   i32x4 __attribute__((ext_vector_type(4)));

__global__ __launch_bounds__(256) void spmv_csr32_kernel(
    const float* __restrict__ x,
    const float* __restrict__ vals,
    const int*   __restrict__ cols,
    const int*   __restrict__ rp,
    float*       __restrict__ y,
    int rows)
{
    const int tid  = blockIdx.x * blockDim.x + threadIdx.x;
    const int row  = tid >> 2;   // 4 threads per row
    const int l4   = tid & 3;
    if (row >= rows) return;

    const int start = rp[row];
    const int end   = rp[row + 1];

    float sum = 0.0f;
    if (end - start == 32) {
        const int j0 = start + l4 * 4;   // lanes cover [0..16) of the row
        const int j1 = j0 + 16;          // and [16..32)

        // Read-once streams: non-temporal (no L2 allocation -> x stays resident).
        const f32x4 v0 = __builtin_nontemporal_load(reinterpret_cast<const f32x4*>(vals + j0));
        const f32x4 v1 = __builtin_nontemporal_load(reinterpret_cast<const f32x4*>(vals + j1));
        const i32x4 c0 = __builtin_nontemporal_load(reinterpret_cast<const i32x4*>(cols + j0));
        const i32x4 c1 = __builtin_nontemporal_load(reinterpret_cast<const i32x4*>(cols + j1));

        // 8 independent gathers, all issued before any use (MLP).
        const float x0 = x[c0[0]];
        const float x1 = x[c0[1]];
        const float x2 = x[c0[2]];
        const float x3 = x[c0[3]];
        const float x4 = x[c1[0]];
        const float x5 = x[c1[1]];
        const float x6 = x[c1[2]];
        const float x7 = x[c1[3]];

        sum = v0[0]*x0 + v0[1]*x1 + v0[2]*x2 + v0[3]*x3
            + v1[0]*x4 + v1[1]*x5 + v1[2]*x6 + v1[3]*x7;
    } else {
        // general-CSR fallback (not hit for this input)
        for (int k = start + l4; k < end; k += 4)
            sum += vals[k] * x[cols[k]];
    }

    // reduce across the 4-lane group
    sum += __shfl_xor(sum, 1);
    sum += __shfl_xor(sum, 2);

    if (l4 == 0) y[row] = sum;
}

extern "C" void kernel_launch(void* const* d_in, const int* in_sizes, int n_in,
                              void* d_out, int out_size, void* d_ws, size_t ws_size,
                              hipStream_t stream)
{
    const float* x    = (const float*)d_in[0];
    const float* vals = (const float*)d_in[1];
    const int*   cols = (const int*)d_in[2];
    const int*   rp   = (const int*)d_in[3];
    float*       y    = (float*)d_out;

    const int rows = out_size;              // 1,000,000
    const int threads = rows * 4;           // 4 lanes per row
    const int block = 256;
    const int grid = (threads + block - 1) / block;

    spmv_csr32_kernel<<<grid, block, 0, stream>>>(x, vals, cols, rp, y, rows);
}